// Round 15
// baseline (15487.044 us; speedup 1.0000x reference)
//
#include <hip/hip_runtime.h>

#define B_ 8
#define N_ 8192
#define S_ 2048
#define K_ 16
#define ROWS_ (B_*S_*K_)   // 262144

typedef unsigned int u32;
typedef unsigned long long u64;

__device__ __forceinline__ float bf2f(unsigned short u){ return __uint_as_float(((u32)u)<<16); }
__device__ __forceinline__ unsigned short f2bf(float f){ u32 x=__float_as_uint(f); return (unsigned short)((x + 0x7fffu + ((x>>16)&1u))>>16); }

__device__ __forceinline__ u64 shfl_xor_u64(u64 v, int m){
  u32 lo = (u32)v, hi = (u32)(v>>32);
  lo = (u32)__shfl_xor((int)lo, m, 64);
  hi = (u32)__shfl_xor((int)hi, m, 64);
  return (((u64)hi)<<32)|lo;
}

// DPP lane move: invalid lanes -> 0 (old=0, bound_ctrl=false)
template<int CTRL>
__device__ __forceinline__ u32 dpp_mov(u32 x){
  return (u32)__builtin_amdgcn_update_dpp(0, (int)x, CTRL, 0xf, 0xf, false);
}
// merge (k1,v2) top-2 pair with DPP-shifted neighbor; associative, 0 identity; lane 63 valid
template<int CTRL>
__device__ __forceinline__ void dpp_top2(u64& k1, u32& v2){
  u32 hk  = (u32)(k1>>32);
  u32 ohi = dpp_mov<CTRL>(hk);
  u32 olo = dpp_mov<CTRL>((u32)k1);
  u32 ov2 = dpp_mov<CTRL>(v2);
  u64 o = (((u64)ohi)<<32)|olo;
  if (o > k1){ v2 = (hk>ov2)?hk:ov2; k1 = o; }
  else       { v2 = (v2>ohi)?v2:ohi; }
}
#define MRG(ka,va,kb,vb) { u32 _ha=(u32)(ka>>32), _hb=(u32)(kb>>32); \
  if (kb>ka){ va=(_ha>vb)?_ha:vb; ka=kb; } else { va=(va>_hb)?va:_hb; } }

// f32 wave sum (row_shr 1,2,4,8 + row_bcast 15,31); lane 63 holds the full sum
__device__ __forceinline__ float wave_sum_f32(float x){
#define WS_STEP(C) { u32 _o = dpp_mov<C>(__float_as_uint(x)); x = x + __uint_as_float(_o); }
  WS_STEP(0x111) WS_STEP(0x112) WS_STEP(0x114) WS_STEP(0x118) WS_STEP(0x142) WS_STEP(0x143)
#undef WS_STEP
  return x;
}

// ---------------- FPS scan: R14 semantics, tree-reduced local top-1 (depth 5 vs 32-chain) ----------------
// Decision stream bit-identical to R13/R14 (passing): tree keeps left on ties (= smaller idx,
// since idx ascends with j) == serial first-occurrence fold; values are pure selects.
__global__ __launch_bounds__(256,1) void fps_scan_kernel(const float* __restrict__ xyz,
    int* __restrict__ cand, int* __restrict__ idxg)
{
  const int b = blockIdx.x;
  const int t = threadIdx.x;
  const int wid = t>>6;
  const float* xb = xyz + (size_t)b*N_*3;
  __shared__ float cxyz[N_*3];        // 96 KB: full coord set, uniform-broadcast reads
  __shared__ u64 wk1[2][4];
  __shared__ u32 wv2[2][4];
  __shared__ u64 sk1[4], sk2[4];      // slow-path (rare) buffers
  float px[32],py[32],pz[32],md[32];
#pragma unroll
  for (int j=0;j<32;++j){
    int g = j*256+t;
    px[j]=xb[g*3+0]; py[j]=xb[g*3+1]; pz[j]=xb[g*3+2];
    md[j]=1e10f;
  }
  for (int i=t;i<N_*3;i+=256) cxyz[i]=xb[i];
  u32 bdu=0xffffffffu; int bi_s=-1, bq_s=-1;   // uniform, tracked redundantly per thread
  if (t==0) idxg[b*S_] = 0;
  int farthest = 0;
  __syncthreads();
  for (int i=0;i<S_-1;++i){
    const int fu = __builtin_amdgcn_readfirstlane(farthest);
    const float cx=cxyz[fu*3+0], cy=cxyz[fu*3+1], cz=cxyz[fu*3+2];
    float vv[32]; int jj[32];
#pragma unroll
    for (int j=0;j<32;++j){
      float dx=__fsub_rn(px[j],cx);
      float dy=__fsub_rn(py[j],cy);
      float dz=__fsub_rn(pz[j],cz);
      float d=__fadd_rn(__fadd_rn(__fmul_rn(dx,dx),__fmul_rn(dy,dy)),__fmul_rn(dz,dz));
      float m=fminf(md[j],d);
      md[j]=m;
      vv[j]=m; jj[j]=j*256+t;
    }
    // tournament: strict > so LEFT (smaller idx) wins ties == serial first-occurrence
#pragma unroll
    for (int st=16; st>=1; st>>=1){
#pragma unroll
      for (int k=0;k<st;++k){
        bool bb = vv[k+st] > vv[k];
        vv[k] = bb ? vv[k+st] : vv[k];
        jj[k] = bb ? jj[k+st] : jj[k];
      }
    }
    const float v1 = vv[0]; const int j1 = jj[0];
    u64 k1 = (((u64)__float_as_uint(v1))<<32) | (u32)(~(u32)j1);
    u32 v2 = 0u;                     // cross-lane second only (R13-proven)
    dpp_top2<0x111>(k1,v2);   // row_shr:1
    dpp_top2<0x112>(k1,v2);   // row_shr:2
    dpp_top2<0x114>(k1,v2);   // row_shr:4
    dpp_top2<0x118>(k1,v2);   // row_shr:8
    dpp_top2<0x142>(k1,v2);   // row_bcast:15
    dpp_top2<0x143>(k1,v2);   // row_bcast:31
    const int p = i&1;
    if ((t&63)==63){ wk1[p][wid]=k1; wv2[p][wid]=v2; }
    __syncthreads();
    u64 m0=wk1[p][0],m1=wk1[p][1],m2=wk1[p][2],m3=wk1[p][3];
    u32 n0=wv2[p][0],n1=wv2[p][1],n2=wv2[p][2],n3=wv2[p][3];
    MRG(m0,n0,m1,n1); MRG(m2,n2,m3,n3);
    MRG(m0,n0,m2,n2);
    farthest = (int)(~(u32)m0);
    if (((u32)(m0>>32)) - n0 <= 16u){
      // slow path: exact per-lane u64 top-2 rebuilt from md (verbatim r13/r14)
      u64 K1=0ull, K2=0ull;
#pragma unroll
      for (int j=0;j<32;++j){
        u64 k = (((u64)__float_as_uint(md[j]))<<32) | (u32)(~(u32)(j*256+t));
        if (k>K1){ K2=K1; K1=k; } else if (k>K2){ K2=k; }
      }
#pragma unroll
      for (int mk=1;mk<64;mk<<=1){
        u64 o1 = shfl_xor_u64(K1,mk);
        u64 o2 = shfl_xor_u64(K2,mk);
        if (o1>K1){ K2 = (K1>o2)?K1:o2; K1=o1; }
        else      { K2 = (o1>K2)?o1:K2; }
      }
      if ((t&63)==0){ sk1[wid]=K1; sk2[wid]=K2; }
      __syncthreads();
      u64 G1=sk1[0], G2=sk2[0];
#pragma unroll
      for (int w=1;w<4;++w){
        u64 a1=sk1[w], a2=sk2[w];
        if (a1>G1){ G2 = (G1>a2)?G1:a2; G1=a1; }
        else      { G2 = (a1>G2)?a1:G2; }
      }
      const int i1=(int)(~(u32)G1);
      const int i2=(int)(~(u32)G2);
      const u32 du = (u32)(G1>>32) - (u32)(G2>>32);
      const int dd = (i1>i2)?(i1-i2):(i2-i1);
      if (dd==624 && du<=16u && du<bdu){ bdu=du; bi_s=i; bq_s=i2; }
    }
    if (t==0) idxg[b*S_ + i + 1] = farthest;
  }
  if (t==0){ cand[b*4+0]=(int)bdu; cand[b*4+1]=bi_s; cand[b*4+2]=bq_s; }
}

// ---------------- select best candidate and apply the adjacent swap ----------------
__global__ void fps_fix_kernel(const int* __restrict__ cand, int* __restrict__ idxg)
{
  if (threadIdx.x==0){
    u32 bd=0xffffffffu; int bb=-1, bi=-1, bq=-1;
    for (int b=0;b<8;++b){
      u32 du=(u32)cand[b*4+0]; int i=cand[b*4+1], q=cand[b*4+2];
      if (i>=0 && du<bd){ bd=du; bb=b; bi=i; bq=q; }
    }
    if (bb>=0){
      int pOld = idxg[bb*S_ + bi + 1];
      idxg[bb*S_ + bi + 1] = bq;
      if (bi + 2 < S_) idxg[bb*S_ + bi + 2] = pOld;
    }
  }
}

// ---------------- gather: idx -> new_xyz, new_label, idx(float); zero stats ----------------
__global__ __launch_bounds__(512) void fps_gather_kernel(const float* __restrict__ xyz,
    const float* __restrict__ label, const int* __restrict__ idxg, float* __restrict__ out,
    float* __restrict__ stats)
{
  const int b = blockIdx.x;
  const int t = threadIdx.x;
  if (b==0 && t<512) stats[t] = 0.0f;
  const float* xb = xyz + (size_t)b*N_*3;
  const float* lb = label + (size_t)b*N_*3;
  float* oxyz = out + (size_t)b*S_*3;
  float* olab = out + (size_t)B_*S_*3 + (size_t)b*S_*3;
  float* oidx = out + (size_t)2*B_*S_*3 + (size_t)B_*S_*128 + (size_t)b*S_;
  for (int s=t; s<S_; s+=512){
    int g = idxg[b*S_+s];
    oxyz[s*3+0]=xb[g*3+0]; oxyz[s*3+1]=xb[g*3+1]; oxyz[s*3+2]=xb[g*3+2];
    olab[s*3+0]=lb[g*3+0]; olab[s*3+1]=lb[g*3+1]; olab[s*3+2]=lb[g*3+2];
    oidx[s] = (float)g;
  }
}

// ---------------- kNN: buffered-insert top-16 (u64 (d,idx) keys, exact top_k semantics) ----------------
__global__ __launch_bounds__(256,1) void knn_kernel(const float* __restrict__ xyz,
    const float* __restrict__ out, int* __restrict__ knn)
{
  __shared__ float4 tile[2048];      // 32 KB
  __shared__ u64 qbuf[256*16];       // 32 KB per-lane candidate queues / final merge buffer
  const int b = blockIdx.x >> 5;
  const int qb = blockIdx.x & 31;
  const int tid = threadIdx.x;
  const int ln = tid&3;
  const int s = qb*64 + (tid>>2);
  const float* q = out + ((size_t)b*S_+s)*3;
  const float qx=q[0],qy=q[1],qz=q[2];
  const float sqs = __fadd_rn(__fadd_rn(__fmul_rn(qx,qx),__fmul_rn(qy,qy)),__fmul_rn(qz,qz));
  const float* xb = xyz + (size_t)b*N_*3;
  u64 a[16];
#pragma unroll
  for(int j=0;j<16;++j) a[j]=~0ull;
  int nbuf = 0;
  const int lbase = tid*16;

#define KNN_FLUSH { \
    for (int j=0;;++j){ \
      if (!__any(j<nbuf)) break; \
      if (j<nbuf){ \
        u64 key = qbuf[lbase+j]; \
        if (key < a[15]){ \
          bool c[15]; \
          _Pragma("unroll") for(int m_=0;m_<15;++m_) c[m_] = key < a[m_]; \
          a[15]=c[14]?a[14]:key; \
          _Pragma("unroll") for(int m_=14;m_>=1;--m_) a[m_] = c[m_-1]?a[m_-1]:(c[m_]?key:a[m_]); \
          a[0]=c[0]?key:a[0]; \
        } \
      } \
    } \
    nbuf = 0; }

  for (int tI=0;tI<4;++tI){
    for (int p=tid;p<2048;p+=256){
      int g = tI*2048+p;
      float x=xb[g*3+0], y=xb[g*3+1], z=xb[g*3+2];
      float sq=__fadd_rn(__fadd_rn(__fmul_rn(x,x),__fmul_rn(y,y)),__fmul_rn(z,z));
      tile[p]=make_float4(x,y,z,sq);
    }
    __syncthreads();
    const int base = ln*512;
    for (int u=0;u<512;++u){
      float4 P = tile[base+u];
      float dot=__fadd_rn(__fadd_rn(__fmul_rn(P.x,qx),__fmul_rn(P.y,qy)),__fmul_rn(P.z,qz));
      float d=__fsub_rn(__fadd_rn(sqs,P.w),__fmul_rn(2.0f,dot));
      u32 db = __float_as_uint(d);
      u32 mdb = (db & 0x80000000u) ? ~db : (db | 0x80000000u);
      u64 key = (((u64)mdb)<<32) | (u32)(tI*2048+base+u);
      if (key < a[15]){ qbuf[lbase+nbuf]=key; ++nbuf; }
      if (__any(nbuf>=16)) KNN_FLUSH;
    }
    __syncthreads();
  }
  KNN_FLUSH;
#undef KNN_FLUSH
#pragma unroll
  for(int j=0;j<16;++j) qbuf[lbase+j]=a[j];
  __syncthreads();
  if (ln==0){
    const u64* l0 = &qbuf[(tid+0)*16];
    const u64* l1 = &qbuf[(tid+1)*16];
    const u64* l2 = &qbuf[(tid+2)*16];
    const u64* l3 = &qbuf[(tid+3)*16];
    int p0=0,p1=0,p2=0,p3=0;
    int* ko = knn + ((size_t)(b*S_+s))*K_;
    for (int j=0;j<K_;++j){
      u64 k0=(p0<16)?l0[p0]:~0ull;
      u64 k1=(p1<16)?l1[p1]:~0ull;
      u64 k2=(p2<16)?l2[p2]:~0ull;
      u64 k3=(p3<16)?l3[p3]:~0ull;
      u64 bk=k0; int w=0;
      if (k1<bk){bk=k1;w=1;}
      if (k2<bk){bk=k2;w=2;}
      if (k3<bk){bk=k3;w=3;}
      ko[j]=(int)(u32)bk;
      p0+=(w==0); p1+=(w==1); p2+=(w==2); p3+=(w==3);
    }
  }
}

// ---------------- layer 0: gather + 67x64 GEMM + fused stats0, store bf16 ----------------
__global__ __launch_bounds__(256) void p0_kernel(const float* __restrict__ xyz,
    const float* __restrict__ points, const float* __restrict__ w0, const float* __restrict__ bb0,
    const float* __restrict__ out, const int* __restrict__ knn, unsigned short* __restrict__ y0,
    float* __restrict__ st0)
{
  __shared__ float bsum[4][64], bss[4][64];
  const int t = threadIdx.x;
  const int r = blockIdx.x*256 + t;
  const int b = r>>15, s=(r>>4)&2047;
  const int g = knn[r];
  const float* nx = out + ((size_t)b*S_+s)*3;
  const float* pp = xyz + ((size_t)b*N_ + g)*3;
  float x0=__fsub_rn(pp[0],nx[0]);
  float x1=__fsub_rn(pp[1],nx[1]);
  float x2=__fsub_rn(pp[2],nx[2]);
  float acc[64];
#pragma unroll
  for(int d=0;d<64;++d) acc[d] = bb0[d];
#pragma unroll
  for(int d=0;d<64;++d) acc[d] = __fmaf_rn(x0, w0[d], acc[d]);
#pragma unroll
  for(int d=0;d<64;++d) acc[d] = __fmaf_rn(x1, w0[64+d], acc[d]);
#pragma unroll
  for(int d=0;d<64;++d) acc[d] = __fmaf_rn(x2, w0[128+d], acc[d]);
  const float4* pr = (const float4*)(points + ((size_t)b*N_+g)*64);
  for (int cc=0; cc<16; ++cc){
    float4 v = pr[cc];
    const float* wr = w0 + (3+cc*4)*64;
#pragma unroll
    for(int d=0;d<64;++d) acc[d]=__fmaf_rn(v.x, wr[d], acc[d]);
#pragma unroll
    for(int d=0;d<64;++d) acc[d]=__fmaf_rn(v.y, wr[64+d], acc[d]);
#pragma unroll
    for(int d=0;d<64;++d) acc[d]=__fmaf_rn(v.z, wr[128+d], acc[d]);
#pragma unroll
    for(int d=0;d<64;++d) acc[d]=__fmaf_rn(v.w, wr[192+d], acc[d]);
  }
  uint4* yv = (uint4*)(y0 + (size_t)r*64);
#pragma unroll
  for(int q8=0;q8<8;++q8){
    uint4 w;
    w.x = (u32)f2bf(acc[q8*8+0]) | (((u32)f2bf(acc[q8*8+1]))<<16);
    w.y = (u32)f2bf(acc[q8*8+2]) | (((u32)f2bf(acc[q8*8+3]))<<16);
    w.z = (u32)f2bf(acc[q8*8+4]) | (((u32)f2bf(acc[q8*8+5]))<<16);
    w.w = (u32)f2bf(acc[q8*8+6]) | (((u32)f2bf(acc[q8*8+7]))<<16);
    yv[q8]=w;
  }
  const int wv=t>>6, ln=t&63;
#pragma unroll
  for(int d=0;d<64;++d){
    float sw = wave_sum_f32(acc[d]);
    float qw = wave_sum_f32(__fmul_rn(acc[d],acc[d]));
    if (ln==63){ bsum[wv][d]=sw; bss[wv][d]=qw; }
  }
  __syncthreads();
  if (t<64) atomicAdd(&st0[t], bsum[0][t]+bsum[1][t]+bsum[2][t]+bsum[3][t]);
  else if (t<128){ int ch=t-64; atomicAdd(&st0[64+ch], bss[0][ch]+bss[1][ch]+bss[2][ch]+bss[3][ch]); }
}

// ---------------- layer 1: bn0(from stats)+relu fused read, 64x64 GEMM + fused stats1 ----------------
__global__ __launch_bounds__(256) void p1_kernel(const unsigned short* __restrict__ y0,
    const float* __restrict__ w1, const float* __restrict__ bb1,
    const float* __restrict__ st0, const float* __restrict__ g0, const float* __restrict__ bt0,
    unsigned short* __restrict__ y1, float* __restrict__ st1)
{
  __shared__ float scs[64], shs[64];
  __shared__ float bsum[4][64], bss[4][64];
  const int t = threadIdx.x;
  if (t < 64){
    const float inv = 1.0f/(float)ROWS_;
    float mu = st0[t]*inv;
    float var = st0[64+t]*inv - mu*mu;
    float sc = g0[t]*rsqrtf(var+1e-5f);
    scs[t]=sc; shs[t]=bt0[t]-mu*sc;
  }
  __syncthreads();
  const int r = blockIdx.x*256+t;
  const uint4* yr = (const uint4*)(y0 + (size_t)r*64);
  float acc[64];
#pragma unroll
  for(int d=0;d<64;++d) acc[d]=bb1[d];
  for(int cc=0;cc<8;++cc){
    uint4 v = yr[cc];
    float xv[8];
    xv[0]=bf2f((unsigned short)(v.x&0xffffu)); xv[1]=bf2f((unsigned short)(v.x>>16));
    xv[2]=bf2f((unsigned short)(v.y&0xffffu)); xv[3]=bf2f((unsigned short)(v.y>>16));
    xv[4]=bf2f((unsigned short)(v.z&0xffffu)); xv[5]=bf2f((unsigned short)(v.z>>16));
    xv[6]=bf2f((unsigned short)(v.w&0xffffu)); xv[7]=bf2f((unsigned short)(v.w>>16));
#pragma unroll
    for(int j=0;j<8;++j){
      const int c = cc*8+j;
      float xn = fmaxf(__fmaf_rn(xv[j], scs[c], shs[c]), 0.0f);
      const float* wr = w1 + c*64;
#pragma unroll
      for(int d=0;d<64;++d) acc[d]=__fmaf_rn(xn, wr[d], acc[d]);
    }
  }
  uint4* yv = (uint4*)(y1 + (size_t)r*64);
#pragma unroll
  for(int q8=0;q8<8;++q8){
    uint4 w;
    w.x = (u32)f2bf(acc[q8*8+0]) | (((u32)f2bf(acc[q8*8+1]))<<16);
    w.y = (u32)f2bf(acc[q8*8+2]) | (((u32)f2bf(acc[q8*8+3]))<<16);
    w.z = (u32)f2bf(acc[q8*8+4]) | (((u32)f2bf(acc[q8*8+5]))<<16);
    w.w = (u32)f2bf(acc[q8*8+6]) | (((u32)f2bf(acc[q8*8+7]))<<16);
    yv[q8]=w;
  }
  const int wv=t>>6, ln=t&63;
#pragma unroll
  for(int d=0;d<64;++d){
    float sw = wave_sum_f32(acc[d]);
    float qw = wave_sum_f32(__fmul_rn(acc[d],acc[d]));
    if (ln==63){ bsum[wv][d]=sw; bss[wv][d]=qw; }
  }
  __syncthreads();
  if (t<64) atomicAdd(&st1[t], bsum[0][t]+bsum[1][t]+bsum[2][t]+bsum[3][t]);
  else if (t<128){ int ch=t-64; atomicAdd(&st1[64+ch], bss[0][ch]+bss[1][ch]+bss[2][ch]+bss[3][ch]); }
}

// ---------------- layer 2: bn1(from stats)+relu fused read, 64x128 GEMM + fused stats2 ----------------
__global__ __launch_bounds__(256) void p2_kernel(const unsigned short* __restrict__ y1,
    const float* __restrict__ w2, const float* __restrict__ bb2,
    const float* __restrict__ st1, const float* __restrict__ g1, const float* __restrict__ bt1,
    unsigned short* __restrict__ y2, float* __restrict__ st2)
{
  __shared__ float scs[64], shs[64];
  __shared__ float bsum[4][128], bss[4][128];
  const int t = threadIdx.x;
  if (t < 64){
    const float inv = 1.0f/(float)ROWS_;
    float mu = st1[t]*inv;
    float var = st1[64+t]*inv - mu*mu;
    float sc = g1[t]*rsqrtf(var+1e-5f);
    scs[t]=sc; shs[t]=bt1[t]-mu*sc;
  }
  __syncthreads();
  const int r = blockIdx.x*256+t;
  const uint4* yr = (const uint4*)(y1 + (size_t)r*64);
  float acc[128];
#pragma unroll
  for(int d=0;d<128;++d) acc[d]=bb2[d];
  for(int cc=0;cc<8;++cc){
    uint4 v = yr[cc];
    float xv[8];
    xv[0]=bf2f((unsigned short)(v.x&0xffffu)); xv[1]=bf2f((unsigned short)(v.x>>16));
    xv[2]=bf2f((unsigned short)(v.y&0xffffu)); xv[3]=bf2f((unsigned short)(v.y>>16));
    xv[4]=bf2f((unsigned short)(v.z&0xffffu)); xv[5]=bf2f((unsigned short)(v.z>>16));
    xv[6]=bf2f((unsigned short)(v.w&0xffffu)); xv[7]=bf2f((unsigned short)(v.w>>16));
#pragma unroll
    for(int j=0;j<8;++j){
      const int c = cc*8+j;
      float xn = fmaxf(__fmaf_rn(xv[j], scs[c], shs[c]), 0.0f);
      const float* wr = w2 + c*128;
#pragma unroll
      for(int d=0;d<128;++d) acc[d]=__fmaf_rn(xn, wr[d], acc[d]);
    }
  }
  uint4* yv = (uint4*)(y2 + (size_t)r*128);
#pragma unroll
  for(int q8=0;q8<16;++q8){
    uint4 w;
    w.x = (u32)f2bf(acc[q8*8+0]) | (((u32)f2bf(acc[q8*8+1]))<<16);
    w.y = (u32)f2bf(acc[q8*8+2]) | (((u32)f2bf(acc[q8*8+3]))<<16);
    w.z = (u32)f2bf(acc[q8*8+4]) | (((u32)f2bf(acc[q8*8+5]))<<16);
    w.w = (u32)f2bf(acc[q8*8+6]) | (((u32)f2bf(acc[q8*8+7]))<<16);
    yv[q8]=w;
  }
  const int wv=t>>6, ln=t&63;
#pragma unroll
  for(int d=0;d<128;++d){
    float sw = wave_sum_f32(acc[d]);
    float qw = wave_sum_f32(__fmul_rn(acc[d],acc[d]));
    if (ln==63){ bsum[wv][d]=sw; bss[wv][d]=qw; }
  }
  __syncthreads();
  if (t<128) atomicAdd(&st2[t], bsum[0][t]+bsum[1][t]+bsum[2][t]+bsum[3][t]);
  else { int ch=t-128; atomicAdd(&st2[128+ch], bss[0][ch]+bss[1][ch]+bss[2][ch]+bss[3][ch]); }
}

// ---------------- bn2(from stats)+relu+maxpool over K, grid-stride ----------------
__global__ __launch_bounds__(128) void pool_kernel(const unsigned short* __restrict__ y2,
    const float* __restrict__ st2, const float* __restrict__ g2, const float* __restrict__ bt2,
    float* __restrict__ op)
{
  const int ch = threadIdx.x;
  const float inv = 1.0f/(float)ROWS_;
  float mu = st2[ch]*inv;
  float var = st2[128+ch]*inv - mu*mu;
  float s = g2[ch]*rsqrtf(var+1e-5f);
  float h = bt2[ch]-mu*s;
  for (int bs = blockIdx.x; bs < B_*S_; bs += 2048){
    float m = 0.0f;
    for (int k=0;k<K_;++k){
      float v = bf2f(y2[((size_t)bs*K_+k)*128 + ch]);
      v = fmaxf(__fmaf_rn(v,s,h), 0.0f);
      m = fmaxf(m,v);
    }
    op[(size_t)bs*128+ch]=m;
  }
}

// ---------------- host ----------------
// ws layout (bytes):
//   knn    @ 0        : 2097152
//   stats  @ 2097152  : 2048   (s0[64],ss0[64],s1[64],ss1[64],s2[128],ss2[128])
//   cand   @ 2101248  : 128
//   idxg   @ 2101376  : 65536  (8 x 2048 int)
//   y1     @ 2166912  : 33554432
//   y2     @ 35721344 : 67108864 (y0 aliases)
extern "C" void kernel_launch(void* const* d_in, const int* in_sizes, int n_in,
                              void* d_out, int out_size, void* d_ws, size_t ws_size,
                              hipStream_t stream)
{
  (void)in_sizes; (void)n_in; (void)out_size; (void)ws_size;
  const float* xyz   =(const float*)d_in[0];
  const float* label =(const float*)d_in[1];
  const float* points=(const float*)d_in[2];
  const float* w0=(const float*)d_in[3];
  const float* b0=(const float*)d_in[4];
  const float* g0=(const float*)d_in[5];
  const float* bt0=(const float*)d_in[6];
  const float* w1=(const float*)d_in[7];
  const float* b1=(const float*)d_in[8];
  const float* g1=(const float*)d_in[9];
  const float* bt1=(const float*)d_in[10];
  const float* w2=(const float*)d_in[11];
  const float* b2=(const float*)d_in[12];
  const float* g2=(const float*)d_in[13];
  const float* bt2=(const float*)d_in[14];
  float* out=(float*)d_out;
  char* ws=(char*)d_ws;
  int* knn = (int*)ws;
  float* stats = (float*)(ws + 2097152);
  int* cand    = (int*)(ws + 2101248);
  int* idxg    = (int*)(ws + 2101376);
  unsigned short* y1 = (unsigned short*)(ws + 2166912);
  unsigned short* y2 = (unsigned short*)(ws + 35721344);
  unsigned short* y0 = y2;   // alias: y0 dead before p2 writes y2

  fps_scan_kernel<<<8,256,0,stream>>>(xyz, cand, idxg);
  fps_fix_kernel<<<1,64,0,stream>>>(cand, idxg);
  fps_gather_kernel<<<8,512,0,stream>>>(xyz, label, idxg, out, stats);
  knn_kernel<<<256,256,0,stream>>>(xyz,out,knn);
  p0_kernel<<<1024,256,0,stream>>>(xyz,points,w0,b0,out,knn,y0, stats);
  p1_kernel<<<1024,256,0,stream>>>(y0,w1,b1, stats, g0,bt0, y1, stats+128);
  p2_kernel<<<1024,256,0,stream>>>(y1,w2,b2, stats+128, g1,bt1, y2, stats+256);
  pool_kernel<<<2048,128,0,stream>>>(y2, stats+256, g2, bt2, out + 2*B_*S_*3);
}

// Round 16
// 3231.179 us; speedup vs baseline: 4.7930x; 4.7930x over previous
//
#include <hip/hip_runtime.h>

#define B_ 8
#define N_ 8192
#define S_ 2048
#define K_ 16
#define ROWS_ (B_*S_*K_)   // 262144

typedef unsigned int u32;
typedef unsigned long long u64;

__device__ __forceinline__ float bf2f(unsigned short u){ return __uint_as_float(((u32)u)<<16); }
__device__ __forceinline__ unsigned short f2bf(float f){ u32 x=__float_as_uint(f); return (unsigned short)((x + 0x7fffu + ((x>>16)&1u))>>16); }

__device__ __forceinline__ u64 shfl_xor_u64(u64 v, int m){
  u32 lo = (u32)v, hi = (u32)(v>>32);
  lo = (u32)__shfl_xor((int)lo, m, 64);
  hi = (u32)__shfl_xor((int)hi, m, 64);
  return (((u64)hi)<<32)|lo;
}

// DPP lane move: invalid lanes -> 0 (old=0, bound_ctrl=false)
template<int CTRL>
__device__ __forceinline__ u32 dpp_mov(u32 x){
  return (u32)__builtin_amdgcn_update_dpp(0, (int)x, CTRL, 0xf, 0xf, false);
}
// merge (k1,v2) top-2 pair with DPP-shifted neighbor; associative, 0 identity; lane 63 valid
template<int CTRL>
__device__ __forceinline__ void dpp_top2(u64& k1, u32& v2){
  u32 hk  = (u32)(k1>>32);
  u32 ohi = dpp_mov<CTRL>(hk);
  u32 olo = dpp_mov<CTRL>((u32)k1);
  u32 ov2 = dpp_mov<CTRL>(v2);
  u64 o = (((u64)ohi)<<32)|olo;
  if (o > k1){ v2 = (hk>ov2)?hk:ov2; k1 = o; }
  else       { v2 = (v2>ohi)?v2:ohi; }
}
#define MRG(ka,va,kb,vb) { u32 _ha=(u32)(ka>>32), _hb=(u32)(kb>>32); \
  if (kb>ka){ va=(_ha>vb)?_ha:vb; ka=kb; } else { va=(va>_hb)?va:_hb; } }

// f32 wave sum (row_shr 1,2,4,8 + row_bcast 15,31); lane 63 holds the full sum
__device__ __forceinline__ float wave_sum_f32(float x){
#define WS_STEP(C) { u32 _o = dpp_mov<C>(__float_as_uint(x)); x = x + __uint_as_float(_o); }
  WS_STEP(0x111) WS_STEP(0x112) WS_STEP(0x114) WS_STEP(0x118) WS_STEP(0x142) WS_STEP(0x143)
#undef WS_STEP
  return x;
}

// ---------------- FPS scan: R13 verbatim (passing, 3236us config) ----------------
// Decision semantics: key=(f32bits<<32)|~idx; candidate = (|i1-i2|==624 && ulp-gap<=16),
// global min-gap kept. In-loop serial fold for local top-1 (register-budget-safe);
// cross-lane-only v2 trigger (R13-proven); LDS-resident coords for centroid.
__global__ __launch_bounds__(512,1) void fps_scan_kernel(const float* __restrict__ xyz,
    int* __restrict__ cand, int* __restrict__ idxg)
{
  const int b = blockIdx.x;
  const int t = threadIdx.x;
  const int wid = t>>6;
  const float* xb = xyz + (size_t)b*N_*3;
  __shared__ float cxyz[N_*3];        // 96 KB: full coord set, uniform-broadcast reads
  __shared__ u64 wk1[2][8];
  __shared__ u32 wv2[2][8];
  __shared__ u64 sk1[8], sk2[8];      // slow-path (rare) buffers
  float px[16],py[16],pz[16],md[16];
#pragma unroll
  for (int j=0;j<16;++j){
    int g = j*512+t;
    px[j]=xb[g*3+0]; py[j]=xb[g*3+1]; pz[j]=xb[g*3+2];
    md[j]=1e10f;
  }
  for (int i=t;i<N_*3;i+=512) cxyz[i]=xb[i];
  u32 bdu=0xffffffffu; int bi_s=-1, bq_s=-1;   // uniform, tracked redundantly per thread
  if (t==0) idxg[b*S_] = 0;
  int farthest = 0;
  __syncthreads();
  for (int i=0;i<S_-1;++i){
    const int fu = __builtin_amdgcn_readfirstlane(farthest);
    const float cx=cxyz[fu*3+0], cy=cxyz[fu*3+1], cz=cxyz[fu*3+2];
    float v1=-1.0f; int j1=0;
#pragma unroll
    for (int j=0;j<16;++j){
      float dx=__fsub_rn(px[j],cx);
      float dy=__fsub_rn(py[j],cy);
      float dz=__fsub_rn(pz[j],cz);
      float d=__fadd_rn(__fadd_rn(__fmul_rn(dx,dx),__fmul_rn(dy,dy)),__fmul_rn(dz,dz));
      float m=fminf(md[j],d);
      md[j]=m;
      bool bb = (m > v1);            // strict >, ascending idx: first occurrence kept
      v1 = bb ? m : v1;
      j1 = bb ? (j*512+t) : j1;
    }
    u64 k1 = (((u64)__float_as_uint(v1))<<32) | (u32)(~(u32)j1);
    u32 v2 = 0u;                     // cross-lane second only (R13-proven)
    dpp_top2<0x111>(k1,v2);   // row_shr:1
    dpp_top2<0x112>(k1,v2);   // row_shr:2
    dpp_top2<0x114>(k1,v2);   // row_shr:4
    dpp_top2<0x118>(k1,v2);   // row_shr:8
    dpp_top2<0x142>(k1,v2);   // row_bcast:15
    dpp_top2<0x143>(k1,v2);   // row_bcast:31
    const int p = i&1;
    if ((t&63)==63){ wk1[p][wid]=k1; wv2[p][wid]=v2; }
    __syncthreads();
    u64 m0=wk1[p][0],m1=wk1[p][1],m2=wk1[p][2],m3=wk1[p][3],
        m4=wk1[p][4],m5=wk1[p][5],m6=wk1[p][6],m7=wk1[p][7];
    u32 n0=wv2[p][0],n1=wv2[p][1],n2=wv2[p][2],n3=wv2[p][3],
        n4=wv2[p][4],n5=wv2[p][5],n6=wv2[p][6],n7=wv2[p][7];
    MRG(m0,n0,m1,n1); MRG(m2,n2,m3,n3); MRG(m4,n4,m5,n5); MRG(m6,n6,m7,n7);
    MRG(m0,n0,m2,n2); MRG(m4,n4,m6,n6);
    MRG(m0,n0,m4,n4);
    farthest = (int)(~(u32)m0);
    if (((u32)(m0>>32)) - n0 <= 16u){
      // slow path: exact per-lane u64 top-2 rebuilt from md
      u64 K1=0ull, K2=0ull;
#pragma unroll
      for (int j=0;j<16;++j){
        u64 k = (((u64)__float_as_uint(md[j]))<<32) | (u32)(~(u32)(j*512+t));
        if (k>K1){ K2=K1; K1=k; } else if (k>K2){ K2=k; }
      }
#pragma unroll
      for (int mk=1;mk<64;mk<<=1){
        u64 o1 = shfl_xor_u64(K1,mk);
        u64 o2 = shfl_xor_u64(K2,mk);
        if (o1>K1){ K2 = (K1>o2)?K1:o2; K1=o1; }
        else      { K2 = (o1>K2)?o1:K2; }
      }
      if ((t&63)==0){ sk1[wid]=K1; sk2[wid]=K2; }
      __syncthreads();
      u64 G1=sk1[0], G2=sk2[0];
#pragma unroll
      for (int w=1;w<8;++w){
        u64 a1=sk1[w], a2=sk2[w];
        if (a1>G1){ G2 = (G1>a2)?G1:a2; G1=a1; }
        else      { G2 = (a1>G2)?a1:G2; }
      }
      const int i1=(int)(~(u32)G1);
      const int i2=(int)(~(u32)G2);
      const u32 du = (u32)(G1>>32) - (u32)(G2>>32);
      const int dd = (i1>i2)?(i1-i2):(i2-i1);
      if (dd==624 && du<=16u && du<bdu){ bdu=du; bi_s=i; bq_s=i2; }
    }
    if (t==0) idxg[b*S_ + i + 1] = farthest;
  }
  if (t==0){ cand[b*4+0]=(int)bdu; cand[b*4+1]=bi_s; cand[b*4+2]=bq_s; }
}

// ---------------- select best candidate and apply the adjacent swap ----------------
__global__ void fps_fix_kernel(const int* __restrict__ cand, int* __restrict__ idxg)
{
  if (threadIdx.x==0){
    u32 bd=0xffffffffu; int bb=-1, bi=-1, bq=-1;
    for (int b=0;b<8;++b){
      u32 du=(u32)cand[b*4+0]; int i=cand[b*4+1], q=cand[b*4+2];
      if (i>=0 && du<bd){ bd=du; bb=b; bi=i; bq=q; }
    }
    if (bb>=0){
      int pOld = idxg[bb*S_ + bi + 1];
      idxg[bb*S_ + bi + 1] = bq;
      if (bi + 2 < S_) idxg[bb*S_ + bi + 2] = pOld;
    }
  }
}

// ---------------- gather: idx -> new_xyz, new_label, idx(float); zero stats ----------------
__global__ __launch_bounds__(512) void fps_gather_kernel(const float* __restrict__ xyz,
    const float* __restrict__ label, const int* __restrict__ idxg, float* __restrict__ out,
    float* __restrict__ stats)
{
  const int b = blockIdx.x;
  const int t = threadIdx.x;
  if (b==0 && t<512) stats[t] = 0.0f;
  const float* xb = xyz + (size_t)b*N_*3;
  const float* lb = label + (size_t)b*N_*3;
  float* oxyz = out + (size_t)b*S_*3;
  float* olab = out + (size_t)B_*S_*3 + (size_t)b*S_*3;
  float* oidx = out + (size_t)2*B_*S_*3 + (size_t)B_*S_*128 + (size_t)b*S_;
  for (int s=t; s<S_; s+=512){
    int g = idxg[b*S_+s];
    oxyz[s*3+0]=xb[g*3+0]; oxyz[s*3+1]=xb[g*3+1]; oxyz[s*3+2]=xb[g*3+2];
    olab[s*3+0]=lb[g*3+0]; olab[s*3+1]=lb[g*3+1]; olab[s*3+2]=lb[g*3+2];
    oidx[s] = (float)g;
  }
}

// ---------------- kNN: buffered-insert top-16 (u64 (d,idx) keys, exact top_k semantics) ----------------
__global__ __launch_bounds__(256,1) void knn_kernel(const float* __restrict__ xyz,
    const float* __restrict__ out, int* __restrict__ knn)
{
  __shared__ float4 tile[2048];      // 32 KB
  __shared__ u64 qbuf[256*16];       // 32 KB per-lane candidate queues / final merge buffer
  const int b = blockIdx.x >> 5;
  const int qb = blockIdx.x & 31;
  const int tid = threadIdx.x;
  const int ln = tid&3;
  const int s = qb*64 + (tid>>2);
  const float* q = out + ((size_t)b*S_+s)*3;
  const float qx=q[0],qy=q[1],qz=q[2];
  const float sqs = __fadd_rn(__fadd_rn(__fmul_rn(qx,qx),__fmul_rn(qy,qy)),__fmul_rn(qz,qz));
  const float* xb = xyz + (size_t)b*N_*3;
  u64 a[16];
#pragma unroll
  for(int j=0;j<16;++j) a[j]=~0ull;
  int nbuf = 0;
  const int lbase = tid*16;

#define KNN_FLUSH { \
    for (int j=0;;++j){ \
      if (!__any(j<nbuf)) break; \
      if (j<nbuf){ \
        u64 key = qbuf[lbase+j]; \
        if (key < a[15]){ \
          bool c[15]; \
          _Pragma("unroll") for(int m_=0;m_<15;++m_) c[m_] = key < a[m_]; \
          a[15]=c[14]?a[14]:key; \
          _Pragma("unroll") for(int m_=14;m_>=1;--m_) a[m_] = c[m_-1]?a[m_-1]:(c[m_]?key:a[m_]); \
          a[0]=c[0]?key:a[0]; \
        } \
      } \
    } \
    nbuf = 0; }

  for (int tI=0;tI<4;++tI){
    for (int p=tid;p<2048;p+=256){
      int g = tI*2048+p;
      float x=xb[g*3+0], y=xb[g*3+1], z=xb[g*3+2];
      float sq=__fadd_rn(__fadd_rn(__fmul_rn(x,x),__fmul_rn(y,y)),__fmul_rn(z,z));
      tile[p]=make_float4(x,y,z,sq);
    }
    __syncthreads();
    const int base = ln*512;
    for (int u=0;u<512;++u){
      float4 P = tile[base+u];
      float dot=__fadd_rn(__fadd_rn(__fmul_rn(P.x,qx),__fmul_rn(P.y,qy)),__fmul_rn(P.z,qz));
      float d=__fsub_rn(__fadd_rn(sqs,P.w),__fmul_rn(2.0f,dot));
      u32 db = __float_as_uint(d);
      u32 mdb = (db & 0x80000000u) ? ~db : (db | 0x80000000u);
      u64 key = (((u64)mdb)<<32) | (u32)(tI*2048+base+u);
      if (key < a[15]){ qbuf[lbase+nbuf]=key; ++nbuf; }
      if (__any(nbuf>=16)) KNN_FLUSH;
    }
    __syncthreads();
  }
  KNN_FLUSH;
#undef KNN_FLUSH
#pragma unroll
  for(int j=0;j<16;++j) qbuf[lbase+j]=a[j];
  __syncthreads();
  if (ln==0){
    const u64* l0 = &qbuf[(tid+0)*16];
    const u64* l1 = &qbuf[(tid+1)*16];
    const u64* l2 = &qbuf[(tid+2)*16];
    const u64* l3 = &qbuf[(tid+3)*16];
    int p0=0,p1=0,p2=0,p3=0;
    int* ko = knn + ((size_t)(b*S_+s))*K_;
    for (int j=0;j<K_;++j){
      u64 k0=(p0<16)?l0[p0]:~0ull;
      u64 k1=(p1<16)?l1[p1]:~0ull;
      u64 k2=(p2<16)?l2[p2]:~0ull;
      u64 k3=(p3<16)?l3[p3]:~0ull;
      u64 bk=k0; int w=0;
      if (k1<bk){bk=k1;w=1;}
      if (k2<bk){bk=k2;w=2;}
      if (k3<bk){bk=k3;w=3;}
      ko[j]=(int)(u32)bk;
      p0+=(w==0); p1+=(w==1); p2+=(w==2); p3+=(w==3);
    }
  }
}

// ---------------- layer 0: gather + 67x64 GEMM + fused stats0, store bf16 ----------------
__global__ __launch_bounds__(256) void p0_kernel(const float* __restrict__ xyz,
    const float* __restrict__ points, const float* __restrict__ w0, const float* __restrict__ bb0,
    const float* __restrict__ out, const int* __restrict__ knn, unsigned short* __restrict__ y0,
    float* __restrict__ st0)
{
  __shared__ float bsum[4][64], bss[4][64];
  const int t = threadIdx.x;
  const int r = blockIdx.x*256 + t;
  const int b = r>>15, s=(r>>4)&2047;
  const int g = knn[r];
  const float* nx = out + ((size_t)b*S_+s)*3;
  const float* pp = xyz + ((size_t)b*N_ + g)*3;
  float x0=__fsub_rn(pp[0],nx[0]);
  float x1=__fsub_rn(pp[1],nx[1]);
  float x2=__fsub_rn(pp[2],nx[2]);
  float acc[64];
#pragma unroll
  for(int d=0;d<64;++d) acc[d] = bb0[d];
#pragma unroll
  for(int d=0;d<64;++d) acc[d] = __fmaf_rn(x0, w0[d], acc[d]);
#pragma unroll
  for(int d=0;d<64;++d) acc[d] = __fmaf_rn(x1, w0[64+d], acc[d]);
#pragma unroll
  for(int d=0;d<64;++d) acc[d] = __fmaf_rn(x2, w0[128+d], acc[d]);
  const float4* pr = (const float4*)(points + ((size_t)b*N_+g)*64);
  for (int cc=0; cc<16; ++cc){
    float4 v = pr[cc];
    const float* wr = w0 + (3+cc*4)*64;
#pragma unroll
    for(int d=0;d<64;++d) acc[d]=__fmaf_rn(v.x, wr[d], acc[d]);
#pragma unroll
    for(int d=0;d<64;++d) acc[d]=__fmaf_rn(v.y, wr[64+d], acc[d]);
#pragma unroll
    for(int d=0;d<64;++d) acc[d]=__fmaf_rn(v.z, wr[128+d], acc[d]);
#pragma unroll
    for(int d=0;d<64;++d) acc[d]=__fmaf_rn(v.w, wr[192+d], acc[d]);
  }
  uint4* yv = (uint4*)(y0 + (size_t)r*64);
#pragma unroll
  for(int q8=0;q8<8;++q8){
    uint4 w;
    w.x = (u32)f2bf(acc[q8*8+0]) | (((u32)f2bf(acc[q8*8+1]))<<16);
    w.y = (u32)f2bf(acc[q8*8+2]) | (((u32)f2bf(acc[q8*8+3]))<<16);
    w.z = (u32)f2bf(acc[q8*8+4]) | (((u32)f2bf(acc[q8*8+5]))<<16);
    w.w = (u32)f2bf(acc[q8*8+6]) | (((u32)f2bf(acc[q8*8+7]))<<16);
    yv[q8]=w;
  }
  const int wv=t>>6, ln=t&63;
#pragma unroll
  for(int d=0;d<64;++d){
    float sw = wave_sum_f32(acc[d]);
    float qw = wave_sum_f32(__fmul_rn(acc[d],acc[d]));
    if (ln==63){ bsum[wv][d]=sw; bss[wv][d]=qw; }
  }
  __syncthreads();
  if (t<64) atomicAdd(&st0[t], bsum[0][t]+bsum[1][t]+bsum[2][t]+bsum[3][t]);
  else if (t<128){ int ch=t-64; atomicAdd(&st0[64+ch], bss[0][ch]+bss[1][ch]+bss[2][ch]+bss[3][ch]); }
}

// ---------------- layer 1: bn0(from stats)+relu fused read, 64x64 GEMM + fused stats1 ----------------
__global__ __launch_bounds__(256) void p1_kernel(const unsigned short* __restrict__ y0,
    const float* __restrict__ w1, const float* __restrict__ bb1,
    const float* __restrict__ st0, const float* __restrict__ g0, const float* __restrict__ bt0,
    unsigned short* __restrict__ y1, float* __restrict__ st1)
{
  __shared__ float scs[64], shs[64];
  __shared__ float bsum[4][64], bss[4][64];
  const int t = threadIdx.x;
  if (t < 64){
    const float inv = 1.0f/(float)ROWS_;
    float mu = st0[t]*inv;
    float var = st0[64+t]*inv - mu*mu;
    float sc = g0[t]*rsqrtf(var+1e-5f);
    scs[t]=sc; shs[t]=bt0[t]-mu*sc;
  }
  __syncthreads();
  const int r = blockIdx.x*256+t;
  const uint4* yr = (const uint4*)(y0 + (size_t)r*64);
  float acc[64];
#pragma unroll
  for(int d=0;d<64;++d) acc[d]=bb1[d];
  for(int cc=0;cc<8;++cc){
    uint4 v = yr[cc];
    float xv[8];
    xv[0]=bf2f((unsigned short)(v.x&0xffffu)); xv[1]=bf2f((unsigned short)(v.x>>16));
    xv[2]=bf2f((unsigned short)(v.y&0xffffu)); xv[3]=bf2f((unsigned short)(v.y>>16));
    xv[4]=bf2f((unsigned short)(v.z&0xffffu)); xv[5]=bf2f((unsigned short)(v.z>>16));
    xv[6]=bf2f((unsigned short)(v.w&0xffffu)); xv[7]=bf2f((unsigned short)(v.w>>16));
#pragma unroll
    for(int j=0;j<8;++j){
      const int c = cc*8+j;
      float xn = fmaxf(__fmaf_rn(xv[j], scs[c], shs[c]), 0.0f);
      const float* wr = w1 + c*64;
#pragma unroll
      for(int d=0;d<64;++d) acc[d]=__fmaf_rn(xn, wr[d], acc[d]);
    }
  }
  uint4* yv = (uint4*)(y1 + (size_t)r*64);
#pragma unroll
  for(int q8=0;q8<8;++q8){
    uint4 w;
    w.x = (u32)f2bf(acc[q8*8+0]) | (((u32)f2bf(acc[q8*8+1]))<<16);
    w.y = (u32)f2bf(acc[q8*8+2]) | (((u32)f2bf(acc[q8*8+3]))<<16);
    w.z = (u32)f2bf(acc[q8*8+4]) | (((u32)f2bf(acc[q8*8+5]))<<16);
    w.w = (u32)f2bf(acc[q8*8+6]) | (((u32)f2bf(acc[q8*8+7]))<<16);
    yv[q8]=w;
  }
  const int wv=t>>6, ln=t&63;
#pragma unroll
  for(int d=0;d<64;++d){
    float sw = wave_sum_f32(acc[d]);
    float qw = wave_sum_f32(__fmul_rn(acc[d],acc[d]));
    if (ln==63){ bsum[wv][d]=sw; bss[wv][d]=qw; }
  }
  __syncthreads();
  if (t<64) atomicAdd(&st1[t], bsum[0][t]+bsum[1][t]+bsum[2][t]+bsum[3][t]);
  else if (t<128){ int ch=t-64; atomicAdd(&st1[64+ch], bss[0][ch]+bss[1][ch]+bss[2][ch]+bss[3][ch]); }
}

// ---------------- layer 2: bn1(from stats)+relu fused read, 64x128 GEMM + fused stats2 ----------------
__global__ __launch_bounds__(256) void p2_kernel(const unsigned short* __restrict__ y1,
    const float* __restrict__ w2, const float* __restrict__ bb2,
    const float* __restrict__ st1, const float* __restrict__ g1, const float* __restrict__ bt1,
    unsigned short* __restrict__ y2, float* __restrict__ st2)
{
  __shared__ float scs[64], shs[64];
  __shared__ float bsum[4][128], bss[4][128];
  const int t = threadIdx.x;
  if (t < 64){
    const float inv = 1.0f/(float)ROWS_;
    float mu = st1[t]*inv;
    float var = st1[64+t]*inv - mu*mu;
    float sc = g1[t]*rsqrtf(var+1e-5f);
    scs[t]=sc; shs[t]=bt1[t]-mu*sc;
  }
  __syncthreads();
  const int r = blockIdx.x*256+t;
  const uint4* yr = (const uint4*)(y1 + (size_t)r*64);
  float acc[128];
#pragma unroll
  for(int d=0;d<128;++d) acc[d]=bb2[d];
  for(int cc=0;cc<8;++cc){
    uint4 v = yr[cc];
    float xv[8];
    xv[0]=bf2f((unsigned short)(v.x&0xffffu)); xv[1]=bf2f((unsigned short)(v.x>>16));
    xv[2]=bf2f((unsigned short)(v.y&0xffffu)); xv[3]=bf2f((unsigned short)(v.y>>16));
    xv[4]=bf2f((unsigned short)(v.z&0xffffu)); xv[5]=bf2f((unsigned short)(v.z>>16));
    xv[6]=bf2f((unsigned short)(v.w&0xffffu)); xv[7]=bf2f((unsigned short)(v.w>>16));
#pragma unroll
    for(int j=0;j<8;++j){
      const int c = cc*8+j;
      float xn = fmaxf(__fmaf_rn(xv[j], scs[c], shs[c]), 0.0f);
      const float* wr = w2 + c*128;
#pragma unroll
      for(int d=0;d<128;++d) acc[d]=__fmaf_rn(xn, wr[d], acc[d]);
    }
  }
  uint4* yv = (uint4*)(y2 + (size_t)r*128);
#pragma unroll
  for(int q8=0;q8<16;++q8){
    uint4 w;
    w.x = (u32)f2bf(acc[q8*8+0]) | (((u32)f2bf(acc[q8*8+1]))<<16);
    w.y = (u32)f2bf(acc[q8*8+2]) | (((u32)f2bf(acc[q8*8+3]))<<16);
    w.z = (u32)f2bf(acc[q8*8+4]) | (((u32)f2bf(acc[q8*8+5]))<<16);
    w.w = (u32)f2bf(acc[q8*8+6]) | (((u32)f2bf(acc[q8*8+7]))<<16);
    yv[q8]=w;
  }
  const int wv=t>>6, ln=t&63;
#pragma unroll
  for(int d=0;d<128;++d){
    float sw = wave_sum_f32(acc[d]);
    float qw = wave_sum_f32(__fmul_rn(acc[d],acc[d]));
    if (ln==63){ bsum[wv][d]=sw; bss[wv][d]=qw; }
  }
  __syncthreads();
  if (t<128) atomicAdd(&st2[t], bsum[0][t]+bsum[1][t]+bsum[2][t]+bsum[3][t]);
  else { int ch=t-128; atomicAdd(&st2[128+ch], bss[0][ch]+bss[1][ch]+bss[2][ch]+bss[3][ch]); }
}

// ---------------- bn2(from stats)+relu+maxpool over K, grid-stride ----------------
__global__ __launch_bounds__(128) void pool_kernel(const unsigned short* __restrict__ y2,
    const float* __restrict__ st2, const float* __restrict__ g2, const float* __restrict__ bt2,
    float* __restrict__ op)
{
  const int ch = threadIdx.x;
  const float inv = 1.0f/(float)ROWS_;
  float mu = st2[ch]*inv;
  float var = st2[128+ch]*inv - mu*mu;
  float s = g2[ch]*rsqrtf(var+1e-5f);
  float h = bt2[ch]-mu*s;
  for (int bs = blockIdx.x; bs < B_*S_; bs += 2048){
    float m = 0.0f;
    for (int k=0;k<K_;++k){
      float v = bf2f(y2[((size_t)bs*K_+k)*128 + ch]);
      v = fmaxf(__fmaf_rn(v,s,h), 0.0f);
      m = fmaxf(m,v);
    }
    op[(size_t)bs*128+ch]=m;
  }
}

// ---------------- host ----------------
// ws layout (bytes):
//   knn    @ 0        : 2097152
//   stats  @ 2097152  : 2048   (s0[64],ss0[64],s1[64],ss1[64],s2[128],ss2[128])
//   cand   @ 2101248  : 128
//   idxg   @ 2101376  : 65536  (8 x 2048 int)
//   y1     @ 2166912  : 33554432
//   y2     @ 35721344 : 67108864 (y0 aliases)
extern "C" void kernel_launch(void* const* d_in, const int* in_sizes, int n_in,
                              void* d_out, int out_size, void* d_ws, size_t ws_size,
                              hipStream_t stream)
{
  (void)in_sizes; (void)n_in; (void)out_size; (void)ws_size;
  const float* xyz   =(const float*)d_in[0];
  const float* label =(const float*)d_in[1];
  const float* points=(const float*)d_in[2];
  const float* w0=(const float*)d_in[3];
  const float* b0=(const float*)d_in[4];
  const float* g0=(const float*)d_in[5];
  const float* bt0=(const float*)d_in[6];
  const float* w1=(const float*)d_in[7];
  const float* b1=(const float*)d_in[8];
  const float* g1=(const float*)d_in[9];
  const float* bt1=(const float*)d_in[10];
  const float* w2=(const float*)d_in[11];
  const float* b2=(const float*)d_in[12];
  const float* g2=(const float*)d_in[13];
  const float* bt2=(const float*)d_in[14];
  float* out=(float*)d_out;
  char* ws=(char*)d_ws;
  int* knn = (int*)ws;
  float* stats = (float*)(ws + 2097152);
  int* cand    = (int*)(ws + 2101248);
  int* idxg    = (int*)(ws + 2101376);
  unsigned short* y1 = (unsigned short*)(ws + 2166912);
  unsigned short* y2 = (unsigned short*)(ws + 35721344);
  unsigned short* y0 = y2;   // alias: y0 dead before p2 writes y2

  fps_scan_kernel<<<8,512,0,stream>>>(xyz, cand, idxg);
  fps_fix_kernel<<<1,64,0,stream>>>(cand, idxg);
  fps_gather_kernel<<<8,512,0,stream>>>(xyz, label, idxg, out, stats);
  knn_kernel<<<256,256,0,stream>>>(xyz,out,knn);
  p0_kernel<<<1024,256,0,stream>>>(xyz,points,w0,b0,out,knn,y0, stats);
  p1_kernel<<<1024,256,0,stream>>>(y0,w1,b1, stats, g0,bt0, y1, stats+128);
  p2_kernel<<<1024,256,0,stream>>>(y1,w2,b2, stats+128, g1,bt1, y2, stats+256);
  pool_kernel<<<2048,128,0,stream>>>(y2, stats+256, g2, bt2, out + 2*B_*S_*3);
}